// Round 6
// baseline (371.928 us; speedup 1.0000x reference)
//
#include <hip/hip_runtime.h>
#include <math.h>

#define K_EMB 512
#define DIM 64
#define NVEC 65536                      // 64*32*32
#define OUT_LOSS 0
#define OUT_Q 1
#define OUT_PERP (1 + NVEC * DIM)       // 4194305
#define OUT_IDX (1 + NVEC * DIM + 1)    // 4194306
#define NBLK 1024
#define AMBIG_CAP 8192
#define EPS2 1e-4f                      // 2*eps candidate margin (bound ~3.3e-5)

// ws layout (bytes):
// [0,2048)    csq[512] f32 (numpy-order)
// [2048]      u32 ambig count
// [2052]      u32 done
// [2056,2064) double sse
// [2112,4160) u32 hist[512]
// [4160,...)  u32 ambig list[AMBIG_CAP]

// numpy pairwise_sum replica for sum(v*v) over 64 elems (products rounded
// before summing, 8 stride-8 chains, pairwise combine) — matches np.sum.
__device__ __forceinline__ float np_pairwise8_sq(const float* v) {
    float r[8];
#pragma unroll
    for (int j = 0; j < 8; ++j) r[j] = __fmul_rn(v[j], v[j]);
#pragma unroll
    for (int i = 8; i < 64; i += 8) {
#pragma unroll
        for (int j = 0; j < 8; ++j) r[j] = __fadd_rn(r[j], __fmul_rn(v[i + j], v[i + j]));
    }
    return __fadd_rn(__fadd_rn(__fadd_rn(r[0], r[1]), __fadd_rn(r[2], r[3])),
                     __fadd_rn(__fadd_rn(r[4], r[5]), __fadd_rn(r[6], r[7])));
}

__global__ void vq_setup(const float* __restrict__ codebook, float* __restrict__ csq) {
    const int k = threadIdx.x;  // 512 threads, 1 block
    csq[k] = np_pairwise8_sq(codebook + (k << 6));
}

// ---------- Phase A: LDS-tiled GEMM-min with top-2 tracking -------------
// Block: 64 vecs. Thread (m_grp=tid&15 -> 4 vecs, n_grp=tid>>4 -> 8 ks).
// 4 macro steps of 128 ks. Accumulators are loop-carried -> must live in
// VGPRs (defeats the remat pathology of rounds 2-5).
__launch_bounds__(256, 3)
__global__ void vq_gemm(const float* __restrict__ inputs, const float* __restrict__ codebook,
                        const float* __restrict__ csq, unsigned* __restrict__ count,
                        unsigned* __restrict__ list, float* __restrict__ out) {
    __shared__ __align__(16) float s_x[64 * 68];    // x_t[kc][m], stride 68
    __shared__ __align__(16) float s_c[64 * 132];   // c_t[kc][n], stride 132; reused as reduce scratch
    __shared__ __align__(16) float s_A[64];
    __shared__ __align__(16) float s_cq[128];

    const int tid = threadIdx.x;
    const int blk = blockIdx.x;

    // stage X tile transposed (coalesced global reads)
    {
        const int m = tid >> 2, p = tid & 3;
        const float4* src = (const float4*)(inputs + ((size_t)(blk * 64 + m) << 6)) + p * 4;
#pragma unroll
        for (int c = 0; c < 4; ++c) {
            float4 v = src[c];
            const int kc = p * 16 + c * 4;
            s_x[(kc + 0) * 68 + m] = v.x;
            s_x[(kc + 1) * 68 + m] = v.y;
            s_x[(kc + 2) * 68 + m] = v.z;
            s_x[(kc + 3) * 68 + m] = v.w;
        }
    }
    __syncthreads();

    // per-vec A = numpy-order ||x||^2 (exact)
    if (tid < 64) {
        float r[8];
#pragma unroll
        for (int j = 0; j < 8; ++j) {
            float v = s_x[j * 68 + tid];
            r[j] = __fmul_rn(v, v);
        }
#pragma unroll
        for (int i = 8; i < 64; i += 8) {
#pragma unroll
            for (int j = 0; j < 8; ++j) {
                float v = s_x[(i + j) * 68 + tid];
                r[j] = __fadd_rn(r[j], __fmul_rn(v, v));
            }
        }
        s_A[tid] = __fadd_rn(__fadd_rn(__fadd_rn(r[0], r[1]), __fadd_rn(r[2], r[3])),
                             __fadd_rn(__fadd_rn(r[4], r[5]), __fadd_rn(r[6], r[7])));
    }

    const int m0 = (tid & 15) * 4;
    const int n_grp = tid >> 4;
    const int n0 = n_grp * 8;

    unsigned long long e1[4], e2[4];
#pragma unroll
    for (int i = 0; i < 4; ++i) { e1[i] = ~0ULL; e2[i] = ~0ULL; }

#pragma unroll 1
    for (int s = 0; s < 4; ++s) {
        __syncthreads();   // protect s_c/s_cq from previous readers
        // stage 128-k codebook tile transposed
        {
            const int n = tid >> 1, h = tid & 1;
            const float4* src = (const float4*)(codebook + ((size_t)(s * 128 + n) << 6)) + h * 8;
#pragma unroll
            for (int j = 0; j < 8; ++j) {
                float4 v = src[j];
                const int kc = h * 32 + j * 4;
                s_c[(kc + 0) * 132 + n] = v.x;
                s_c[(kc + 1) * 132 + n] = v.y;
                s_c[(kc + 2) * 132 + n] = v.z;
                s_c[(kc + 3) * 132 + n] = v.w;
            }
        }
        if (tid < 128) s_cq[tid] = csq[s * 128 + tid];
        __syncthreads();

        float acc[4][8];
#pragma unroll
        for (int i = 0; i < 4; ++i)
#pragma unroll
            for (int j = 0; j < 8; ++j) acc[i][j] = 0.f;

#pragma unroll 8
        for (int kc = 0; kc < 64; ++kc) {
            const float4 xv = *(const float4*)&s_x[kc * 68 + m0];
            const float4 c0 = *(const float4*)&s_c[kc * 132 + n0];
            const float4 c1 = *(const float4*)&s_c[kc * 132 + n0 + 4];
            const float xs[4] = {xv.x, xv.y, xv.z, xv.w};
            const float cs[8] = {c0.x, c0.y, c0.z, c0.w, c1.x, c1.y, c1.z, c1.w};
#pragma unroll
            for (int i = 0; i < 4; ++i)
#pragma unroll
                for (int j = 0; j < 8; ++j)
                    acc[i][j] = __builtin_fmaf(xs[i], cs[j], acc[i][j]);
        }

        // fold: d2 = fl(fl(A - fl(2*acc)) + csq), track top-2 as packed u64
        const float4 Av = *(const float4*)&s_A[m0];
        const float Ai[4] = {Av.x, Av.y, Av.z, Av.w};
        const float4 q0 = *(const float4*)&s_cq[n0];
        const float4 q1 = *(const float4*)&s_cq[n0 + 4];
        const float cqj[8] = {q0.x, q0.y, q0.z, q0.w, q1.x, q1.y, q1.z, q1.w};
#pragma unroll
        for (int i = 0; i < 4; ++i) {
#pragma unroll
            for (int j = 0; j < 8; ++j) {
                float d2 = __fadd_rn(__fsub_rn(Ai[i], __fmul_rn(2.0f, acc[i][j])), cqj[j]);
                unsigned long long e =
                    ((unsigned long long)__float_as_uint(d2) << 32) | (unsigned)(s * 128 + n0 + j);
                if (e < e1[i]) { e2[i] = e1[i]; e1[i] = e; }
                else if (e < e2[i]) e2[i] = e;
            }
        }
    }

    // cross-thread top-2 merge (reuse s_c as u64 scratch: 16 KB <= 33 KB)
    __syncthreads();
    unsigned long long* r1 = (unsigned long long*)s_c;
    unsigned long long* r2 = r1 + 1024;
#pragma unroll
    for (int i = 0; i < 4; ++i) {
        r1[(m0 + i) * 16 + n_grp] = e1[i];
        r2[(m0 + i) * 16 + n_grp] = e2[i];
    }
    __syncthreads();
    if (tid < 64) {
        unsigned long long E1 = ~0ULL, E2 = ~0ULL;
#pragma unroll
        for (int g = 0; g < 16; ++g) {
            unsigned long long a = r1[tid * 16 + g], b = r2[tid * 16 + g];
            if (a < E1) { E2 = (E1 < b) ? E1 : b; E1 = a; }
            else if (a < E2) E2 = a;
        }
        const int vec = blk * 64 + tid;
        out[OUT_IDX + vec] = (float)(unsigned)E1;   // low 32 bits = k
        float b1 = __uint_as_float((unsigned)(E1 >> 32));
        float b2 = __uint_as_float((unsigned)(E2 >> 32));
        if (__fsub_rn(b2, b1) <= EPS2) {            // ambiguous: exact replay needed
            unsigned pos = atomicAdd(count, 1u);
            if (pos < AMBIG_CAP) list[pos] = (unsigned)vec;
        }
    }
}

// ---------- Phase A2: exact numpy-order replay for ambiguous vecs ----------
__global__ void vq_fix(const float* __restrict__ inputs, const float* __restrict__ codebook,
                       const float* __restrict__ csq, const unsigned* __restrict__ count,
                       const unsigned* __restrict__ list, float* __restrict__ out) {
    const int lane = threadIdx.x & 63;
    const int wid = (blockIdx.x * 256 + threadIdx.x) >> 6;   // 256 waves total
    int n = (int)*count; if (n > AMBIG_CAP) n = AMBIG_CAP;
    for (int i = wid; i < n; i += 256) {
        const int vec = (int)list[i];
        const float* x = inputs + ((size_t)vec << 6);        // wave-uniform
        const float A = np_pairwise8_sq(x);
        unsigned long long best = ~0ULL;
#pragma unroll 1
        for (int r = 0; r < 8; ++r) {
            const int k = lane * 8 + r;
            const float* c = codebook + (k << 6);
            float p[8] = {0.f, 0.f, 0.f, 0.f, 0.f, 0.f, 0.f, 0.f};
#pragma unroll
            for (int ii = 0; ii < 64; ii += 8)
#pragma unroll
                for (int j = 0; j < 8; ++j) p[j] = __builtin_fmaf(x[ii + j], c[ii + j], p[j]);
            float dot = __fadd_rn(__fadd_rn(__fadd_rn(p[0], p[1]), __fadd_rn(p[2], p[3])),
                                  __fadd_rn(__fadd_rn(p[4], p[5]), __fadd_rn(p[6], p[7])));
            float d2 = __fadd_rn(__fsub_rn(A, __fmul_rn(2.0f, dot)), csq[k]);
            unsigned long long e = ((unsigned long long)__float_as_uint(d2) << 32) | (unsigned)k;
            if (e < best) best = e;
        }
#pragma unroll
        for (int off = 32; off > 0; off >>= 1) {
            unsigned long long o = __shfl_down(best, off);
            if (o < best) best = o;
        }
        if (lane == 0) out[OUT_IDX + vec] = (float)(unsigned)best;  // ties -> smallest k
    }
}

// ---------- Phase B: epilogue (quantized write, hist, SSE, stats) ----------
__launch_bounds__(256)
__global__ void vq_epi(const float* __restrict__ inputs, const float* __restrict__ codebook,
                       float* __restrict__ out, unsigned* __restrict__ hist,
                       double* __restrict__ sse, unsigned* __restrict__ done) {
    __shared__ unsigned s_h[512];
    __shared__ float s_w[4];
    __shared__ float s_wsm[4];
    __shared__ int s_last;
    const int tid = threadIdx.x;
    s_h[tid] = 0u; s_h[tid + 256] = 0u;
    __syncthreads();

    const int vloc = tid >> 2, qt = tid & 3;
    const int vec = blockIdx.x * 64 + vloc;
    const int k = (int)out[OUT_IDX + vec];
    const float4* c4 = (const float4*)(codebook + ((size_t)k << 6)) + qt * 4;
    const float4* x4 = (const float4*)(inputs + ((size_t)vec << 6)) + qt * 4;
    float4* o4 = (float4*)(out + OUT_Q + ((size_t)vec << 6)) + qt * 4;
    float es = 0.f;
#pragma unroll
    for (int j = 0; j < 4; ++j) {
        float4 qv = c4[j], xv = x4[j];
        o4[j] = qv;
        float d0 = qv.x - xv.x; es = __builtin_fmaf(d0, d0, es);
        float d1 = qv.y - xv.y; es = __builtin_fmaf(d1, d1, es);
        float d2 = qv.z - xv.z; es = __builtin_fmaf(d2, d2, es);
        float d3 = qv.w - xv.w; es = __builtin_fmaf(d3, d3, es);
    }
    if (qt == 0) atomicAdd(&s_h[k], 1u);
#pragma unroll
    for (int off = 32; off > 0; off >>= 1) es += __shfl_down(es, off);
    if ((tid & 63) == 0) s_w[tid >> 6] = es;
    __syncthreads();
    if (tid == 0) atomicAdd(sse, (double)(((s_w[0] + s_w[1]) + (s_w[2] + s_w[3]))));
    if (s_h[tid]) atomicAdd(&hist[tid], s_h[tid]);
    if (s_h[tid + 256]) atomicAdd(&hist[tid + 256], s_h[tid + 256]);
    __threadfence();
    __syncthreads();
    if (tid == 0) {
        unsigned n = atomicAdd(done, 1u);
        s_last = (n == NBLK - 1) ? 1 : 0;
    }
    __syncthreads();

    if (s_last) {
        __threadfence();
        float v = 0.f;
#pragma unroll
        for (int r = 0; r < 2; ++r) {
            int kk = tid + 256 * r;
            unsigned cnt = atomicAdd(&hist[kk], 0u);   // coherent read
            float pr = (float)cnt / 65536.0f;
            v = __fadd_rn(v, __fmul_rn(pr, logf(__fadd_rn(pr, 1e-10f))));
        }
#pragma unroll
        for (int off = 32; off > 0; off >>= 1) v += __shfl_down(v, off);
        if ((tid & 63) == 0) s_wsm[tid >> 6] = v;
        __syncthreads();
        if (tid == 0) {
            float S = __fadd_rn(__fadd_rn(s_wsm[0], s_wsm[1]), __fadd_rn(s_wsm[2], s_wsm[3]));
            out[OUT_PERP] = expf(-S);
            double sv = atomicAdd(sse, 0.0);          // coherent read
            float m = (float)(sv / 4194304.0);        // exact /2^22
            out[OUT_LOSS] = __fadd_rn(m, __fmul_rn(0.25f, m));
        }
    }
}

extern "C" void kernel_launch(void* const* d_in, const int* in_sizes, int n_in,
                              void* d_out, int out_size, void* d_ws, size_t ws_size,
                              hipStream_t stream) {
    const float* inputs   = (const float*)d_in[0];
    const float* codebook = (const float*)d_in[1];
    float* out = (float*)d_out;
    float*    csq   = (float*)d_ws;
    unsigned* count = (unsigned*)((char*)d_ws + 2048);
    unsigned* done  = (unsigned*)((char*)d_ws + 2052);
    double*   sse   = (double*)((char*)d_ws + 2056);
    unsigned* hist  = (unsigned*)((char*)d_ws + 2112);
    unsigned* list  = (unsigned*)((char*)d_ws + 4160);

    hipMemsetAsync(d_ws, 0, 4160 + 4 * AMBIG_CAP, stream);
    vq_setup<<<1, 512, 0, stream>>>(codebook, csq);
    vq_gemm<<<NBLK, 256, 0, stream>>>(inputs, codebook, csq, count, list, out);
    vq_fix<<<64, 256, 0, stream>>>(inputs, codebook, csq, count, list, out);
    vq_epi<<<NBLK, 256, 0, stream>>>(inputs, codebook, out, hist, sse, done);
}

// Round 7
// 187.414 us; speedup vs baseline: 1.9845x; 1.9845x over previous
//
#include <hip/hip_runtime.h>
#include <math.h>

#define K_EMB 512
#define DIM 64
#define NVEC 65536                      // 64*32*32
#define OUT_LOSS 0
#define OUT_Q 1
#define OUT_PERP (1 + NVEC * DIM)       // 4194305
#define OUT_IDX (1 + NVEC * DIM + 1)    // 4194306
#define NBLK 1024
#define EPS2 1e-4f                      // top-2 ambiguity margin (bound ~3.3e-5)
#define FIX_CAP 16

// ws layout (bytes): [0,2048) csq[512] | [2056,2064) double sse | [2112,4160) u32 hist[512]

// numpy pairwise_sum replica for sum(v*v) over 64 elems (products rounded
// before summing, 8 stride-8 chains, pairwise combine) — matches np.sum.
__device__ __forceinline__ float np_pairwise8_sq(const float* v) {
    float r[8];
#pragma unroll
    for (int j = 0; j < 8; ++j) r[j] = __fmul_rn(v[j], v[j]);
#pragma unroll
    for (int i = 8; i < 64; i += 8) {
#pragma unroll
        for (int j = 0; j < 8; ++j) r[j] = __fadd_rn(r[j], __fmul_rn(v[i + j], v[i + j]));
    }
    return __fadd_rn(__fadd_rn(__fadd_rn(r[0], r[1]), __fadd_rn(r[2], r[3])),
                     __fadd_rn(__fadd_rn(r[4], r[5]), __fadd_rn(r[6], r[7])));
}

__global__ void vq_setup(const float* __restrict__ codebook, float* __restrict__ csq) {
    const int k = threadIdx.x;  // 512 threads, 1 block
    csq[k] = np_pairwise8_sq(codebook + (k << 6));
}

// One kernel: LDS-tiled GEMM-min (top-2) + in-block exact replay for ambiguous
// vecs + epilogue (idx, quantized, LDS hist -> global, per-block sse atomic).
// NO threadfence / done-counter: the final-stats kernel boundary provides
// device-wide visibility (the round-6 fence pattern cost ~167 us standalone).
__launch_bounds__(256, 3)
__global__ void vq_main(const float* __restrict__ inputs, const float* __restrict__ codebook,
                        const float* __restrict__ csq, unsigned* __restrict__ hist,
                        double* __restrict__ sse, float* __restrict__ out) {
    __shared__ __align__(16) float s_x[64 * 64];    // x_t[kc][m], 16 KB (stride 64: <=2-way, free)
    __shared__ __align__(16) float s_c[64 * 132];   // c_t[kc][n], 33.8 KB; reused as u64 scratch
    __shared__ __align__(16) float s_A[64];
    __shared__ __align__(16) float s_cq[128];
    __shared__ unsigned long long s_e[64];
    __shared__ int s_fix[FIX_CAP];
    __shared__ int s_nfix;
    __shared__ unsigned s_h[512];
    __shared__ float s_w[4];

    const int tid = threadIdx.x;
    const int blk = blockIdx.x;

    if (tid == 0) s_nfix = 0;
    s_h[tid] = 0u; s_h[tid + 256] = 0u;

    // stage X tile transposed (coalesced global reads)
    {
        const int m = tid >> 2, p = tid & 3;
        const float4* src = (const float4*)(inputs + ((size_t)(blk * 64 + m) << 6)) + p * 4;
#pragma unroll
        for (int c = 0; c < 4; ++c) {
            float4 v = src[c];
            const int kc = p * 16 + c * 4;
            s_x[(kc + 0) * 64 + m] = v.x;
            s_x[(kc + 1) * 64 + m] = v.y;
            s_x[(kc + 2) * 64 + m] = v.z;
            s_x[(kc + 3) * 64 + m] = v.w;
        }
    }
    __syncthreads();

    // per-vec A = numpy-order ||x||^2 (exact)
    if (tid < 64) {
        float r[8];
#pragma unroll
        for (int j = 0; j < 8; ++j) {
            float v = s_x[j * 64 + tid];
            r[j] = __fmul_rn(v, v);
        }
#pragma unroll
        for (int i = 8; i < 64; i += 8) {
#pragma unroll
            for (int j = 0; j < 8; ++j) {
                float v = s_x[(i + j) * 64 + tid];
                r[j] = __fadd_rn(r[j], __fmul_rn(v, v));
            }
        }
        s_A[tid] = __fadd_rn(__fadd_rn(__fadd_rn(r[0], r[1]), __fadd_rn(r[2], r[3])),
                             __fadd_rn(__fadd_rn(r[4], r[5]), __fadd_rn(r[6], r[7])));
    }

    const int m0 = (tid & 15) * 4;
    const int n_grp = tid >> 4;
    const int n0 = n_grp * 8;

    unsigned long long e1[4], e2[4];
#pragma unroll
    for (int i = 0; i < 4; ++i) { e1[i] = ~0ULL; e2[i] = ~0ULL; }

#pragma unroll 1
    for (int s = 0; s < 4; ++s) {
        __syncthreads();   // protect s_c/s_cq from previous readers
        {
            const int n = tid >> 1, h = tid & 1;
            const float4* src = (const float4*)(codebook + ((size_t)(s * 128 + n) << 6)) + h * 8;
#pragma unroll
            for (int j = 0; j < 8; ++j) {
                float4 v = src[j];
                const int kc = h * 32 + j * 4;
                s_c[(kc + 0) * 132 + n] = v.x;
                s_c[(kc + 1) * 132 + n] = v.y;
                s_c[(kc + 2) * 132 + n] = v.z;
                s_c[(kc + 3) * 132 + n] = v.w;
            }
        }
        if (tid < 128) s_cq[tid] = csq[s * 128 + tid];
        __syncthreads();

        float acc[4][8];
#pragma unroll
        for (int i = 0; i < 4; ++i)
#pragma unroll
            for (int j = 0; j < 8; ++j) acc[i][j] = 0.f;

#pragma unroll 8
        for (int kc = 0; kc < 64; ++kc) {
            const float4 xv = *(const float4*)&s_x[kc * 64 + m0];
            const float4 c0 = *(const float4*)&s_c[kc * 132 + n0];
            const float4 c1 = *(const float4*)&s_c[kc * 132 + n0 + 4];
            const float xs[4] = {xv.x, xv.y, xv.z, xv.w};
            const float cs[8] = {c0.x, c0.y, c0.z, c0.w, c1.x, c1.y, c1.z, c1.w};
#pragma unroll
            for (int i = 0; i < 4; ++i)
#pragma unroll
                for (int j = 0; j < 8; ++j)
                    acc[i][j] = __builtin_fmaf(xs[i], cs[j], acc[i][j]);
        }

        const float4 Av = *(const float4*)&s_A[m0];
        const float Ai[4] = {Av.x, Av.y, Av.z, Av.w};
        const float4 q0 = *(const float4*)&s_cq[n0];
        const float4 q1 = *(const float4*)&s_cq[n0 + 4];
        const float cqj[8] = {q0.x, q0.y, q0.z, q0.w, q1.x, q1.y, q1.z, q1.w};
#pragma unroll
        for (int i = 0; i < 4; ++i) {
#pragma unroll
            for (int j = 0; j < 8; ++j) {
                float d2 = __fadd_rn(__fsub_rn(Ai[i], __fmul_rn(2.0f, acc[i][j])), cqj[j]);
                unsigned long long e =
                    ((unsigned long long)__float_as_uint(d2) << 32) | (unsigned)(s * 128 + n0 + j);
                if (e < e1[i]) { e2[i] = e1[i]; e1[i] = e; }
                else if (e < e2[i]) e2[i] = e;
            }
        }
    }

    // cross-thread top-2 merge (overlay u64 scratch on s_c: 16 KB <= 33 KB)
    __syncthreads();
    unsigned long long* r1 = (unsigned long long*)s_c;
    unsigned long long* r2 = r1 + 1024;
#pragma unroll
    for (int i = 0; i < 4; ++i) {
        r1[(m0 + i) * 16 + n_grp] = e1[i];
        r2[(m0 + i) * 16 + n_grp] = e2[i];
    }
    __syncthreads();
    if (tid < 64) {
        unsigned long long E1 = ~0ULL, E2 = ~0ULL;
#pragma unroll
        for (int g = 0; g < 16; ++g) {
            unsigned long long a = r1[tid * 16 + g], b = r2[tid * 16 + g];
            if (a < E1) { E2 = (E1 < b) ? E1 : b; E1 = a; }
            else if (a < E2) E2 = a;
        }
        s_e[tid] = E1;
        float b1 = __uint_as_float((unsigned)(E1 >> 32));
        float b2 = __uint_as_float((unsigned)(E2 >> 32));
        if (__fsub_rn(b2, b1) <= EPS2) {            // ambiguous: exact replay needed
            int pos = atomicAdd(&s_nfix, 1);
            if (pos < FIX_CAP) s_fix[pos] = tid;
        }
    }
    __syncthreads();

    // in-block exact numpy-order replay for ambiguous vecs (rare; one wave each)
    {
        int nf = s_nfix; if (nf > FIX_CAP) nf = FIX_CAP;
        const int wid = tid >> 6, lane = tid & 63;
        for (int f = wid; f < nf; f += 4) {
            const int v = s_fix[f];
            float r[8];
#pragma unroll
            for (int j = 0; j < 8; ++j) {
                float t = s_x[j * 64 + v];
                r[j] = __fmul_rn(t, t);
            }
#pragma unroll
            for (int i = 8; i < 64; i += 8) {
#pragma unroll
                for (int j = 0; j < 8; ++j) {
                    float t = s_x[(i + j) * 64 + v];
                    r[j] = __fadd_rn(r[j], __fmul_rn(t, t));
                }
            }
            const float A = __fadd_rn(__fadd_rn(__fadd_rn(r[0], r[1]), __fadd_rn(r[2], r[3])),
                                      __fadd_rn(__fadd_rn(r[4], r[5]), __fadd_rn(r[6], r[7])));
            unsigned long long best = ~0ULL;
#pragma unroll 1
            for (int r8 = 0; r8 < 8; ++r8) {
                const int k = lane * 8 + r8;
                const float* c = codebook + (k << 6);
                float p[8] = {0.f, 0.f, 0.f, 0.f, 0.f, 0.f, 0.f, 0.f};
#pragma unroll
                for (int ii = 0; ii < 64; ii += 8)
#pragma unroll
                    for (int j = 0; j < 8; ++j)
                        p[j] = __builtin_fmaf(s_x[(ii + j) * 64 + v], c[ii + j], p[j]);
                float dot = __fadd_rn(__fadd_rn(__fadd_rn(p[0], p[1]), __fadd_rn(p[2], p[3])),
                                      __fadd_rn(__fadd_rn(p[4], p[5]), __fadd_rn(p[6], p[7])));
                float d2 = __fadd_rn(__fsub_rn(A, __fmul_rn(2.0f, dot)), csq[k]);
                unsigned long long e = ((unsigned long long)__float_as_uint(d2) << 32) | (unsigned)k;
                if (e < best) best = e;
            }
#pragma unroll
            for (int off = 32; off > 0; off >>= 1) {
                unsigned long long o = __shfl_down(best, off);
                if (o < best) best = o;
            }
            if (lane == 0) s_e[v] = best;   // ties -> smallest k (first occurrence)
        }
    }
    __syncthreads();

    // epilogue: idx + LDS hist + quantized + sse
    if (tid < 64) {
        const unsigned kf = (unsigned)s_e[tid];
        out[OUT_IDX + blk * 64 + tid] = (float)kf;
        atomicAdd(&s_h[kf], 1u);
    }
    {
        const int vloc = tid >> 2, qt = tid & 3;
        const unsigned kq = (unsigned)s_e[vloc];
        const float4* c4 = (const float4*)(codebook + ((size_t)kq << 6)) + qt * 4;
        float4* o4 = (float4*)(out + OUT_Q + ((size_t)(blk * 64 + vloc) << 6)) + qt * 4;
        float es = 0.f;
#pragma unroll
        for (int j = 0; j < 4; ++j) {
            float4 qv = c4[j];
            o4[j] = qv;
            const int d = qt * 16 + j * 4;
            float d0 = qv.x - s_x[(d + 0) * 64 + vloc]; es = __builtin_fmaf(d0, d0, es);
            float d1 = qv.y - s_x[(d + 1) * 64 + vloc]; es = __builtin_fmaf(d1, d1, es);
            float d2 = qv.z - s_x[(d + 2) * 64 + vloc]; es = __builtin_fmaf(d2, d2, es);
            float d3 = qv.w - s_x[(d + 3) * 64 + vloc]; es = __builtin_fmaf(d3, d3, es);
        }
#pragma unroll
        for (int off = 32; off > 0; off >>= 1) es += __shfl_down(es, off);
        if ((tid & 63) == 0) s_w[tid >> 6] = es;
    }
    __syncthreads();
    if (tid == 0) atomicAdd(sse, (double)(((s_w[0] + s_w[1]) + (s_w[2] + s_w[3]))));
    if (s_h[tid]) atomicAdd(&hist[tid], s_h[tid]);
    if (s_h[tid + 256]) atomicAdd(&hist[tid + 256], s_h[tid + 256]);
}

// final stats: kernel boundary gives device-wide visibility of hist/sse
__global__ void vq_final(const unsigned* __restrict__ hist, const double* __restrict__ sse,
                         float* __restrict__ out) {
    __shared__ float s_wsm[8];
    const int k = threadIdx.x;  // 512 threads
    float pr = (float)hist[k] / 65536.0f;
    float v = __fmul_rn(pr, logf(__fadd_rn(pr, 1e-10f)));
#pragma unroll
    for (int off = 32; off > 0; off >>= 1) v += __shfl_down(v, off);
    if ((k & 63) == 0) s_wsm[k >> 6] = v;
    __syncthreads();
    if (k == 0) {
        float S = 0.f;
#pragma unroll
        for (int i = 0; i < 8; ++i) S += s_wsm[i];
        out[OUT_PERP] = expf(-S);
        float m = (float)(*sse / 4194304.0);          // exact /2^22
        out[OUT_LOSS] = __fadd_rn(m, __fmul_rn(0.25f, m));
    }
}

extern "C" void kernel_launch(void* const* d_in, const int* in_sizes, int n_in,
                              void* d_out, int out_size, void* d_ws, size_t ws_size,
                              hipStream_t stream) {
    const float* inputs   = (const float*)d_in[0];
    const float* codebook = (const float*)d_in[1];
    float* out = (float*)d_out;
    float*    csq  = (float*)d_ws;
    double*   sse  = (double*)((char*)d_ws + 2056);
    unsigned* hist = (unsigned*)((char*)d_ws + 2112);

    hipMemsetAsync(d_ws, 0, 4160, stream);
    vq_setup<<<1, 512, 0, stream>>>(codebook, csq);
    vq_main<<<NBLK, 256, 0, stream>>>(inputs, codebook, csq, hist, sse, out);
    vq_final<<<1, 512, 0, stream>>>(hist, sse, out);
}

// Round 8
// 151.479 us; speedup vs baseline: 2.4553x; 1.2372x over previous
//
#include <hip/hip_runtime.h>
#include <math.h>

#define K_EMB 512
#define DIM 64
#define NVEC 65536                      // 64*32*32
#define OUT_LOSS 0
#define OUT_Q 1
#define OUT_PERP (1 + NVEC * DIM)       // 4194305
#define OUT_IDX (1 + NVEC * DIM + 1)    // 4194306
#define EPS2 1e-4f                      // ambiguity margin (fast-path err bound ~2e-5)
#define FIX_CAP 32                      // per 128-vec block

typedef __attribute__((ext_vector_type(8))) short short8;   // 8 bf16 (4 VGPRs)
typedef __attribute__((ext_vector_type(4))) float float4v;  // MFMA acc

// ws layout (bytes):
// [0,2048)        csq[512] fp32 (numpy-order)
// [2048,2056)     double sse
// [2112,4160)     u32 hist[512]
// [4224,69760)    ahi: codebook hi-bf16 A-fragments [t=32][step=2][lane=64][8]
// [69760,135296)  alo: codebook lo-bf16 A-fragments
// [135296,168064) csqf: per-(t,lane) float4 of csq for the fold

__device__ __forceinline__ unsigned short bf16_rn(float f) {
    unsigned u = __float_as_uint(f);
    return (unsigned short)((u + 0x7FFFu + ((u >> 16) & 1u)) >> 16);
}

// numpy pairwise_sum replica for sum(v*v) over 64 elems (products rounded
// before summing, 8 stride-8 chains, pairwise combine) — matches np.sum.
__device__ __forceinline__ float np_pairwise8_sq(const float* v) {
    float r[8];
#pragma unroll
    for (int j = 0; j < 8; ++j) r[j] = __fmul_rn(v[j], v[j]);
#pragma unroll
    for (int i = 8; i < 64; i += 8) {
#pragma unroll
        for (int j = 0; j < 8; ++j) r[j] = __fadd_rn(r[j], __fmul_rn(v[i + j], v[i + j]));
    }
    return __fadd_rn(__fadd_rn(__fadd_rn(r[0], r[1]), __fadd_rn(r[2], r[3])),
                     __fadd_rn(__fadd_rn(r[4], r[5]), __fadd_rn(r[6], r[7])));
}

__global__ void vq_setup(const float* __restrict__ codebook, float* __restrict__ csq) {
    const int k = threadIdx.x;  // 512 threads, 1 block
    csq[k] = np_pairwise8_sq(codebook + (k << 6));
}

// Precompute codebook MFMA A-fragments (hi/lo bf16) in exact per-lane order,
// plus per-(tile,lane) csq float4. One-time per launch; L2-resident afterwards.
__global__ void vq_frag(const float* __restrict__ codebook, const float* __restrict__ csq,
                        unsigned short* __restrict__ ahi, unsigned short* __restrict__ alo,
                        float4* __restrict__ csqf) {
    const int id = blockIdx.x * 256 + threadIdx.x;   // 4096 total
    const int t = id >> 7, step = (id >> 6) & 1, lane = id & 63;
    const int m = t * 16 + (lane & 15);              // codebook row (A m-index)
    const int kb = step * 32 + (lane >> 4) * 8;      // A k-index base
    const float* src = codebook + (m << 6) + kb;
    short8 h, l;
#pragma unroll
    for (int j = 0; j < 8; ++j) {
        float f = src[j];
        unsigned short hv = bf16_rn(f);
        float lof = f - __uint_as_float(((unsigned)hv) << 16);
        h[j] = (short)hv;
        l[j] = (short)bf16_rn(lof);
    }
    const int fo = ((t * 2 + step) * 64 + lane) * 8;
    *(short8*)(ahi + fo) = h;
    *(short8*)(alo + fo) = l;
    if (step == 0) {
        const int k0 = t * 16 + (lane >> 4) * 4;     // rows covered by this lane's acc regs
        csqf[t * 64 + lane] = make_float4(csq[k0], csq[k0 + 1], csq[k0 + 2], csq[k0 + 3]);
    }
}

// Main: MFMA distance GEMM (bf16 hi/lo x3) + top-2 + in-block exact replay +
// epilogue. Block = 128 vecs (4 waves x 32 vecs), grid = 512.
__launch_bounds__(256, 4)
__global__ void vq_main(const float* __restrict__ inputs, const float* __restrict__ codebook,
                        const float* __restrict__ csq, const unsigned short* __restrict__ ahi,
                        const unsigned short* __restrict__ alo, const float4* __restrict__ csqf,
                        unsigned* __restrict__ hist, double* __restrict__ sse,
                        float* __restrict__ out) {
    __shared__ __align__(16) float s_x[128 * 68];    // x rows, stride 68 (bank-spread)
    __shared__ float s_A[128];
    __shared__ unsigned long long s_e[128];
    __shared__ unsigned s_h[512];
    __shared__ int s_fix[FIX_CAP];
    __shared__ int s_nfix;
    __shared__ float s_w[4];

    const int tid = threadIdx.x;
    const int wave = tid >> 6, lane = tid & 63;
    const int blk = blockIdx.x;
    const int vbase = blk * 128;

    if (tid == 0) s_nfix = 0;
    s_h[tid] = 0u; s_h[tid + 256] = 0u;

    // stage x (coalesced b128): it*1024 + tid*4 floats -> row it*16+(tid>>4), col (tid&15)*4
    {
        const float4* src = (const float4*)(inputs + ((size_t)vbase << 6));
#pragma unroll
        for (int it = 0; it < 8; ++it) {
            float4 v = src[it * 256 + tid];
            const int row = it * 16 + (tid >> 4), col = (tid & 15) * 4;
            *(float4*)&s_x[row * 68 + col] = v;
        }
    }
    __syncthreads();

    // exact numpy-order ||x||^2 per vec (threads 0..127)
    if (tid < 128) {
        const float* xr = &s_x[tid * 68];
        s_A[tid] = np_pairwise8_sq(xr);
    }
    __syncthreads();

    // build B-fragments (x) for this wave's 32 vecs: 2 vec-tiles x 2 k-steps, hi+lo
    short8 bhi[2][2], blo[2][2];
    float Av[2];
#pragma unroll
    for (int vt = 0; vt < 2; ++vt) {
        const int vrow = wave * 32 + vt * 16 + (lane & 15);
        Av[vt] = s_A[vrow];
#pragma unroll
        for (int step = 0; step < 2; ++step) {
            const int kb = step * 32 + (lane >> 4) * 8;
            float4 f0 = *(const float4*)&s_x[vrow * 68 + kb];
            float4 f1 = *(const float4*)&s_x[vrow * 68 + kb + 4];
            const float fs[8] = {f0.x, f0.y, f0.z, f0.w, f1.x, f1.y, f1.z, f1.w};
            short8 h, l;
#pragma unroll
            for (int j = 0; j < 8; ++j) {
                unsigned short hv = bf16_rn(fs[j]);
                float lof = fs[j] - __uint_as_float(((unsigned)hv) << 16);
                h[j] = (short)hv;
                l[j] = (short)bf16_rn(lof);
            }
            bhi[vt][step] = h;
            blo[vt][step] = l;
        }
    }

    unsigned long long e1[2] = {~0ULL, ~0ULL}, e2[2] = {~0ULL, ~0ULL};

#pragma unroll 2
    for (int t = 0; t < 32; ++t) {
        const int fo0 = ((t * 2 + 0) * 64 + lane) * 8;
        const int fo1 = ((t * 2 + 1) * 64 + lane) * 8;
        short8 ah0 = *(const short8*)(ahi + fo0);
        short8 ah1 = *(const short8*)(ahi + fo1);
        short8 al0 = *(const short8*)(alo + fo0);
        short8 al1 = *(const short8*)(alo + fo1);
        float4 cs = csqf[t * 64 + lane];
        const float csr[4] = {cs.x, cs.y, cs.z, cs.w};
#pragma unroll
        for (int vt = 0; vt < 2; ++vt) {
            float4v acc = {0.f, 0.f, 0.f, 0.f};
            acc = __builtin_amdgcn_mfma_f32_16x16x32_bf16(ah0, bhi[vt][0], acc, 0, 0, 0);
            acc = __builtin_amdgcn_mfma_f32_16x16x32_bf16(ah1, bhi[vt][1], acc, 0, 0, 0);
            acc = __builtin_amdgcn_mfma_f32_16x16x32_bf16(ah0, blo[vt][0], acc, 0, 0, 0);
            acc = __builtin_amdgcn_mfma_f32_16x16x32_bf16(ah1, blo[vt][1], acc, 0, 0, 0);
            acc = __builtin_amdgcn_mfma_f32_16x16x32_bf16(al0, bhi[vt][0], acc, 0, 0, 0);
            acc = __builtin_amdgcn_mfma_f32_16x16x32_bf16(al1, bhi[vt][1], acc, 0, 0, 0);
#pragma unroll
            for (int r = 0; r < 4; ++r) {
                // D mapping: col=lane&15 (=vec), row=(lane>>4)*4+r (=codeword in tile)
                float d2 = __fadd_rn(__fsub_rn(Av[vt], __fmul_rn(2.0f, acc[r])), csr[r]);
                const unsigned k = (unsigned)(t * 16 + (lane >> 4) * 4 + r);
                unsigned long long e = ((unsigned long long)__float_as_uint(d2) << 32) | k;
                if (e < e1[vt]) { e2[vt] = e1[vt]; e1[vt] = e; }
                else if (e < e2[vt]) e2[vt] = e;
            }
        }
    }

    // merge the 4 lane-groups holding different k-subsets of the same vec
#pragma unroll
    for (int vt = 0; vt < 2; ++vt) {
#pragma unroll
        for (int off = 16; off <= 32; off <<= 1) {
            unsigned long long o1 = __shfl_xor(e1[vt], off);
            unsigned long long o2 = __shfl_xor(e2[vt], off);
            if (o1 < e1[vt]) { e2[vt] = (e1[vt] < o2) ? e1[vt] : o2; e1[vt] = o1; }
            else if (o1 < e2[vt]) e2[vt] = o1;
        }
        if (lane < 16) {
            const int vloc = wave * 32 + vt * 16 + lane;
            s_e[vloc] = e1[vt];
            float b1 = __uint_as_float((unsigned)(e1[vt] >> 32));
            float b2 = __uint_as_float((unsigned)(e2[vt] >> 32));
            if (__fsub_rn(b2, b1) <= EPS2) {     // ambiguous -> exact replay
                int pos = atomicAdd(&s_nfix, 1);
                if (pos < FIX_CAP) s_fix[pos] = vloc;
            }
        }
    }
    __syncthreads();

    // exact numpy-order replay for ambiguous vecs (one wave each)
    {
        int nf = s_nfix; if (nf > FIX_CAP) nf = FIX_CAP;
        for (int f = wave; f < nf; f += 4) {
            const int vloc = s_fix[f];
            const float* xr = &s_x[vloc * 68];   // wave-uniform -> LDS broadcast
            const float A = s_A[vloc];           // already exact numpy-order
            unsigned long long best = ~0ULL;
#pragma unroll 1
            for (int r8 = 0; r8 < 8; ++r8) {
                const int k = lane * 8 + r8;
                const float* c = codebook + (k << 6);
                float p[8] = {0.f, 0.f, 0.f, 0.f, 0.f, 0.f, 0.f, 0.f};
#pragma unroll
                for (int ii = 0; ii < 64; ii += 8)
#pragma unroll
                    for (int j = 0; j < 8; ++j)
                        p[j] = __builtin_fmaf(xr[ii + j], c[ii + j], p[j]);
                float dot = __fadd_rn(__fadd_rn(__fadd_rn(p[0], p[1]), __fadd_rn(p[2], p[3])),
                                      __fadd_rn(__fadd_rn(p[4], p[5]), __fadd_rn(p[6], p[7])));
                float d2 = __fadd_rn(__fsub_rn(A, __fmul_rn(2.0f, dot)), csq[k]);
                unsigned long long e = ((unsigned long long)__float_as_uint(d2) << 32) | (unsigned)k;
                if (e < best) best = e;
            }
#pragma unroll
            for (int off = 32; off > 0; off >>= 1) {
                unsigned long long o = __shfl_down(best, off);
                if (o < best) best = o;
            }
            if (lane == 0) s_e[vloc] = best;     // equal-d2 ties -> smallest k
        }
    }
    __syncthreads();

    // epilogue: indices + LDS hist
    if (tid < 128) {
        const unsigned kf = (unsigned)s_e[tid];
        out[OUT_IDX + vbase + tid] = (float)kf;
        atomicAdd(&s_h[kf], 1u);
    }
    // quantized (fully coalesced b128) + sse
    {
        float4* dst = (float4*)(out + OUT_Q + ((size_t)vbase << 6));
        float es = 0.f;
#pragma unroll
        for (int it = 0; it < 8; ++it) {
            const int row = it * 16 + (tid >> 4), col = (tid & 15) * 4;
            const unsigned k = (unsigned)s_e[row];
            float4 qv = *(const float4*)(codebook + ((size_t)k << 6) + col);
            dst[it * 256 + tid] = qv;
            float4 xv = *(const float4*)&s_x[row * 68 + col];
            float d0 = qv.x - xv.x; es = __builtin_fmaf(d0, d0, es);
            float d1 = qv.y - xv.y; es = __builtin_fmaf(d1, d1, es);
            float d2 = qv.z - xv.z; es = __builtin_fmaf(d2, d2, es);
            float d3 = qv.w - xv.w; es = __builtin_fmaf(d3, d3, es);
        }
#pragma unroll
        for (int off = 32; off > 0; off >>= 1) es += __shfl_down(es, off);
        if (lane == 0) s_w[wave] = es;
    }
    __syncthreads();
    if (tid == 0) atomicAdd(sse, (double)(((s_w[0] + s_w[1]) + (s_w[2] + s_w[3]))));
    if (s_h[tid]) atomicAdd(&hist[tid], s_h[tid]);
    if (s_h[tid + 256]) atomicAdd(&hist[tid + 256], s_h[tid + 256]);
}

// final stats: kernel boundary gives device-wide visibility of hist/sse
__global__ void vq_final(const unsigned* __restrict__ hist, const double* __restrict__ sse,
                         float* __restrict__ out) {
    __shared__ float s_wsm[8];
    const int k = threadIdx.x;  // 512 threads
    float pr = (float)hist[k] / 65536.0f;
    float v = __fmul_rn(pr, logf(__fadd_rn(pr, 1e-10f)));
#pragma unroll
    for (int off = 32; off > 0; off >>= 1) v += __shfl_down(v, off);
    if ((k & 63) == 0) s_wsm[k >> 6] = v;
    __syncthreads();
    if (k == 0) {
        float S = 0.f;
#pragma unroll
        for (int i = 0; i < 8; ++i) S += s_wsm[i];
        out[OUT_PERP] = expf(-S);
        float m = (float)(*sse / 4194304.0);          // exact /2^22
        out[OUT_LOSS] = __fadd_rn(m, __fmul_rn(0.25f, m));
    }
}

extern "C" void kernel_launch(void* const* d_in, const int* in_sizes, int n_in,
                              void* d_out, int out_size, void* d_ws, size_t ws_size,
                              hipStream_t stream) {
    const float* inputs   = (const float*)d_in[0];
    const float* codebook = (const float*)d_in[1];
    float* out = (float*)d_out;
    float*          csq  = (float*)d_ws;
    double*         sse  = (double*)((char*)d_ws + 2048);
    unsigned*       hist = (unsigned*)((char*)d_ws + 2112);
    unsigned short* ahi  = (unsigned short*)((char*)d_ws + 4224);
    unsigned short* alo  = (unsigned short*)((char*)d_ws + 69760);
    float4*         csqf = (float4*)((char*)d_ws + 135296);

    hipMemsetAsync((char*)d_ws + 2048, 0, 2112, stream);   // sse + hist
    vq_setup<<<1, 512, 0, stream>>>(codebook, csq);
    vq_frag<<<16, 256, 0, stream>>>(codebook, csq, ahi, alo, csqf);
    vq_main<<<512, 256, 0, stream>>>(inputs, codebook, csq, ahi, alo, csqf, hist, sse, out);
    vq_final<<<1, 512, 0, stream>>>(hist, sse, out);
}